// Round 17
// baseline (254.682 us; speedup 1.0000x reference)
//
#include <hip/hip_runtime.h>

// LSTM-GCN single step from (H=0, C=0).
// Collapsed math: Fg gate dead (C_prev=0), cheb(H,..)=bh, peephole wc[0],wc[1] dead.
//
// R21: R20 never ran (container failed twice -- infra, not correctness).
// Resubmit R20 unchanged except one hardening: sortdeg's Phase C scan now has
// ALL 1024 threads execute the shfl-scan and ONE uniform __syncthreads (no
// barriers under divergent control flow -- the only new UB-risk site R20
// introduced). Plan unchanged: 6 dispatches (scan2 deleted -> consumers scan
// the 196 raw tile sums locally; deg_sum merged into sortdeg via PRE-SCALING:
// records carry -w, sortdeg writes xs2[s]=dinv[s]*x[s], gather applies dinv[d]
// at its write -- same product, re-associated).

#define FDIM 32
#define MAX_N 100000
#define MAX_E 1600000
#define CBSH 8                                // 256 nodes per coarse bucket
#define CB 256
#define MAX_NB ((MAX_N + CB - 1) / CB)        // 391 buckets max
#define NBLK 512                              // blocks in each edge pass
#define SCAN_TILE 2048                        // elements per scan block (256 thr x 8)
#define GNB 64                                // nodes per gates block
#define PERBLK 3136                           // staged records per block (>= 3128)

typedef int   iv4 __attribute__((ext_vector_type(4)));
typedef float fv4 __attribute__((ext_vector_type(4)));
__device__ __forceinline__ iv4 nt_i4(const int* p)   { return __builtin_nontemporal_load((const iv4*)p); }
__device__ __forceinline__ fv4 nt_f4(const float* p) { return __builtin_nontemporal_load((const fv4*)p); }

__device__ float g_deg[MAX_N];                    // dinv (written by sortdeg)
__device__ int   g_part2[2 * MAX_NB * NBLK + 1];  // [dst bins | src bins] counts->offsets
__device__ int   g_blk[1024];                     // RAW scan tile sums (no scan2)
__device__ uint2 g_rec[MAX_E];                    // dst-sorted {src<<8|dst_loc, w}
__device__ uint2 g_srec[MAX_E];                   // src-sorted {src_loc, w}
__device__ int   g_row[MAX_N + 1];                // per-node CSR row starts
__device__ __attribute__((aligned(16))) int   g_src2[MAX_E];   // CSR src, node-sorted
__device__ __attribute__((aligned(16))) float g_nrm2[MAX_E];   // CSR -w, node-sorted
__device__ __attribute__((aligned(16))) float g_xs2[MAX_N * FDIM];  // dinv[s]*x[s]
__device__ float g_tx1[MAX_N * FDIM];             // L_hat @ x

// One edge pass, NO global atomics: dual LDS histograms of dst>>8 and src>>8,
// flushed non-atomically to g_part2[bin*NBLK + block]. Edge reads int4.
__global__ __launch_bounds__(256) void hist2_kernel(const int* __restrict__ ei,
                                                    int E, int n_nodes, int nbuck,
                                                    int per_blk) {
    __shared__ int hd[MAX_NB];
    __shared__ int hs[MAX_NB];
    for (int i = threadIdx.x; i < nbuck; i += 256) { hd[i] = 0; hs[i] = 0; }
    __syncthreads();
    int start = blockIdx.x * per_blk;            // per_blk % 4 == 0 -> aligned
    int end = start + per_blk;
    if (end > E) end = E;
    for (int base = start; base < end; base += 1024) {
        int e = base + threadIdx.x * 4;
        if (e + 4 <= end) {
            int4 s4 = *(const int4*)(ei + e);
            int4 d4 = *(const int4*)(ei + E + e);
#define H2(S, D) if ((unsigned)(S) < (unsigned)n_nodes && (unsigned)(D) < (unsigned)n_nodes) { \
                atomicAdd(&hd[(D) >> CBSH], 1); atomicAdd(&hs[(S) >> CBSH], 1); }
            H2(s4.x, d4.x) H2(s4.y, d4.y) H2(s4.z, d4.z) H2(s4.w, d4.w)
#undef H2
        } else if (e < end) {
            for (int q = e; q < end; ++q) {
                int s = ei[q], d = ei[E + q];
                if ((unsigned)s >= (unsigned)n_nodes || (unsigned)d >= (unsigned)n_nodes)
                    continue;
                atomicAdd(&hd[d >> CBSH], 1);
                atomicAdd(&hs[s >> CBSH], 1);
            }
        }
    }
    __syncthreads();
    for (int i = threadIdx.x; i < nbuck; i += 256) {
        g_part2[i * NBLK + blockIdx.x] = hd[i];
        g_part2[(nbuck + i) * NBLK + blockIdx.x] = hs[i];
    }
    if (blockIdx.x == 0 && threadIdx.x == 0)
        g_part2[2 * nbuck * NBLK] = 0;        // scan sentinel
}

// Per-tile exclusive scan; writes RAW tile totals to g_blk (consumers scan it
// locally -- scan2 kernel deleted). n ~ 400K -> 196 tiles (<= 256).
__global__ __launch_bounds__(256) void scan1_kernel(int n) {
    __shared__ int sh[256];
    int tid = threadIdx.x;
    int base = blockIdx.x * SCAN_TILE + tid * 8;
    int v[8];
#pragma unroll
    for (int i = 0; i < 8; ++i) v[i] = (base + i < n) ? g_part2[base + i] : 0;
    int tsum = 0;
#pragma unroll
    for (int i = 0; i < 8; ++i) tsum += v[i];
    sh[tid] = tsum;
    __syncthreads();
    for (int off = 1; off < 256; off <<= 1) {
        int t = (tid >= off) ? sh[tid - off] : 0;
        __syncthreads();
        sh[tid] += t;
        __syncthreads();
    }
    if (tid == 255) g_blk[blockIdx.x] = sh[255];
    int run = sh[tid] - tsum;   // exclusive offset within tile
#pragma unroll
    for (int i = 0; i < 8; ++i) {
        if (base + i < n) g_part2[base + i] = run;
        run += v[i];
    }
}

// Two phases (dst records into g_rec, src records into g_srec). Tile offsets
// scanned locally from raw g_blk. Per phase: counts/bases from the scanned
// matrix, 512-wide LDS Hillis-Steele for local run bases, cursor-scatter into
// staged LDS + per-record global position, then coalesced burst write-out.
__global__ __launch_bounds__(256) void scatter_burst_kernel(const int* __restrict__ ei,
                                                            const float* __restrict__ w,
                                                            int E, int n_nodes, int nbuck,
                                                            int per_blk, int ntile) {
    __shared__ int   toff[256];
    __shared__ int   cnt[512];
    __shared__ int   sc[512];
    __shared__ int   gb[MAX_NB];
    __shared__ int   cur[MAX_NB];
    __shared__ uint2 staged[PERBLK];
    __shared__ int   gpos[PERBLK];
    int tid = threadIdx.x;
    int blk = blockIdx.x;
    int start = blk * per_blk;
    int end = start + per_blk;
    if (end > E) end = E;

    // local exclusive scan of raw tile sums (ntile <= 256)
    int orig = (tid < ntile) ? g_blk[tid] : 0;
    toff[tid] = orig;
    __syncthreads();
    for (int off = 1; off < 256; off <<= 1) {
        int v = (tid >= off) ? toff[tid - off] : 0;
        __syncthreads();
        toff[tid] += v;
        __syncthreads();
    }
    toff[tid] -= orig;                         // exclusive
    __syncthreads();
#define SCN(idx) (g_part2[idx] + toff[(idx) >> 11])

    for (int phase = 0; phase < 2; ++phase) {
        cnt[tid] = 0; cnt[tid + 256] = 0;
        __syncthreads();
        for (int i = tid; i < nbuck; i += 256) {
            int flat = (phase * nbuck + i) * NBLK + blk;
            int g0 = SCN(flat);
            int g1 = SCN(flat + 1);                // flat successor = run end
            gb[i] = g0 - phase * E;                // src space is [E,2E)
            cnt[i] = g1 - g0;
        }
        __syncthreads();
        sc[tid] = cnt[tid]; sc[tid + 256] = cnt[tid + 256];
        __syncthreads();
        for (int off = 1; off < 512; off <<= 1) {  // inclusive scan, 512 wide
            int v0 = (tid >= off) ? sc[tid - off] : 0;
            int v1 = sc[tid + 256 - off];          // tid+256 >= off always
            __syncthreads();
            sc[tid] += v0; sc[tid + 256] += v1;
            __syncthreads();
        }
        for (int i = tid; i < nbuck; i += 256) cur[i] = sc[i] - cnt[i];
        __syncthreads();
#define SB1(S, D, W)                                                            \
        {   int s = (S), d = (D);                                               \
            if ((unsigned)s < (unsigned)n_nodes && (unsigned)d < (unsigned)n_nodes) { \
                int key = phase ? s : d;                                        \
                int bin = key >> CBSH;                                          \
                float w0 = (s == d) ? 0.f : (W);   /* self-loops: w=0 */        \
                unsigned pay = phase ? (unsigned)(s & (CB - 1))                 \
                    : (((unsigned)s << CBSH) | (unsigned)(d & (CB - 1)));       \
                int p = atomicAdd(&cur[bin], 1);   /* LDS cursor */             \
                staged[p] = make_uint2(pay, __float_as_uint(w0));               \
                gpos[p] = gb[bin] + (p - (sc[bin] - cnt[bin]));                 \
            } }
        for (int base = start; base < end; base += 1024) {
            int e = base + tid * 4;
            if (e + 4 <= end) {
                iv4 s4 = nt_i4(ei + e);
                iv4 d4 = nt_i4(ei + E + e);
                fv4 w4 = nt_f4(w + e);
                SB1(s4[0], d4[0], w4[0]) SB1(s4[1], d4[1], w4[1])
                SB1(s4[2], d4[2], w4[2]) SB1(s4[3], d4[3], w4[3])
            } else if (e < end) {
                for (int q = e; q < end; ++q) SB1(ei[q], ei[E + q], w[q])
            }
        }
#undef SB1
        __syncthreads();
        int tot = sc[511];                         // valid records in this chunk
        if (phase == 0) {
            for (int t = tid; t < tot; t += 256) g_rec[gpos[t]] = staged[t];
        } else {
            for (int t = tid; t < tot; t += 256) g_srec[gpos[t]] = staged[t];
        }
        __syncthreads();
    }
#undef SCN
}

// MERGED deg_sum + fine_sort (+ x pre-scale). One block per bucket b (256
// nodes), 1024 threads. Phase A: count dst-local nodes (g_rec) AND accumulate
// deg (g_srec) in LDS. Phase B: dinv = rsqrt(deg) -> g_deg; write pre-scaled
// xs2[n] = dinv[n]*x[n] (coalesced float4). Phase C: hierarchical scan ->
// absolute g_row; reorder records into per-node CSR with nrm = -w (no dinv
// needed -- that's what makes the merge legal; gather applies dinv[d]).
// ALL barriers are uniform (every thread reaches every __syncthreads).
__global__ __launch_bounds__(1024) void sortdeg_kernel(const float* __restrict__ x,
                                                       int E, int n_nodes, int nbuck,
                                                       int ntile) {
    __shared__ int   toff[256];
    __shared__ int   cnt[CB];
    __shared__ int   cur[CB];
    __shared__ float ldeg[CB];
    __shared__ int   wsum[4];
    int tid = threadIdx.x;
    int b = blockIdx.x;

    // local exclusive scan of raw tile sums (uniform barriers)
    int orig = 0;
    if (tid < 256) { orig = (tid < ntile) ? g_blk[tid] : 0; toff[tid] = orig; }
    __syncthreads();
    for (int off = 1; off < 256; off <<= 1) {
        int v = (tid < 256 && tid >= off) ? toff[tid - off] : 0;
        __syncthreads();
        if (tid < 256) toff[tid] += v;
        __syncthreads();
    }
    if (tid < 256) toff[tid] -= orig;          // exclusive
    if (tid < CB) { cnt[tid] = 0; ldeg[tid] = 0.f; }
    __syncthreads();
#define SCN(idx) (g_part2[idx] + toff[(idx) >> 11])
    int rsD = SCN(b * NBLK);
    int reD = SCN((b + 1) * NBLK);             // b==nbuck-1 hits first src bin (= E)
    int rsS = SCN((nbuck + b) * NBLK) - E;
    int reS = SCN((nbuck + b + 1) * NBLK) - E; // b==nbuck-1 hits sentinel (2E)
#undef SCN

    // Phase A: dst-local counts + src-bucket degree accumulation
    for (int i = rsD + tid; i < reD; i += 1024)
        atomicAdd(&cnt[g_rec[i].x & (CB - 1)], 1);
    for (int i = rsS + tid; i < reS; i += 1024) {
        uint2 r = g_srec[i];
        atomicAdd(&ldeg[r.x], __uint_as_float(r.y));
    }
    __syncthreads();

    // Phase B: dinv -> g_deg; pre-scale x rows into xs2
    if (tid < CB) {
        float dg = ldeg[tid];
        float dv = (dg > 0.f) ? rsqrtf(dg) : 0.f;
        ldeg[tid] = dv;                        // reuse as dinv store
        int node = (b << CBSH) + tid;
        if (node < n_nodes) g_deg[node] = dv;
    }
    __syncthreads();
    for (int t = tid; t < CB * FDIM / 4; t += 1024) {
        int q = t * 4;
        int loc = q >> 5;
        int node = (b << CBSH) + loc;
        if (node < n_nodes) {
            fv4 xv = *(const fv4*)&x[node * FDIM + (q & 31)];
            float dv = ldeg[loc];
            xv[0] *= dv; xv[1] *= dv; xv[2] *= dv; xv[3] *= dv;
            *(fv4*)&g_xs2[node * FDIM + (q & 31)] = xv;
        }
    }

    // Phase C: hierarchical scan -> g_row. UNIFORM: all 16 waves run the
    // shfl-scan (waves >= 4 on garbage, results discarded), one shared barrier.
    {
        int lane = tid & 63;
        int wave = tid >> 6;
        int v = (tid < CB) ? cnt[tid] : 0;
        int inc = v;
#pragma unroll
        for (int off = 1; off < 64; off <<= 1) {
            int t = __shfl_up(inc, off, 64);
            if (lane >= off) inc += t;
        }
        if (tid < CB && lane == 63) wsum[wave] = inc;
        __syncthreads();                       // uniform
        if (tid < CB) {
            int wo = 0;
#pragma unroll
            for (int ww = 0; ww < 4; ++ww) wo += (ww < wave) ? wsum[ww] : 0;
            int start = rsD + wo + (inc - v);  // exclusive
            cur[tid] = start;
            int node = (b << CBSH) + tid;
            if (node < n_nodes) g_row[node] = start;
        }
    }
    if (b == nbuck - 1 && tid == 0) g_row[n_nodes] = reD;
    __syncthreads();
    for (int i = rsD + tid; i < reD; i += 1024) {
        uint2 r = g_rec[i];
        int loc = r.x & (CB - 1);
        int pos = atomicAdd(&cur[loc], 1);     // LDS atomic
        g_src2[pos] = (int)(r.x >> CBSH);
        g_nrm2[pos] = -__uint_as_float(r.y);   // raw -w; dinv applied elsewhere
    }
}

// Half-wave (32 lanes = 32 features) per node, REGISTER accumulators (dual),
// CSR stream nt, 8-deep unroll. Reads PRE-SCALED xs2; applies dinv[d] once at
// the write (tx1[d] = dinv[d] * sum(-w * dinv[s]*x[s])).
__global__ __launch_bounds__(256) void gather_kernel(int n_nodes) {
    int t = blockIdx.x * blockDim.x + threadIdx.x;
    int node = t >> 5;
    int f = t & 31;
    if (node >= n_nodes) return;
    int i = g_row[node];
    int end = g_row[node + 1];
    float acc = 0.f, accB = 0.f;
    while (i < end && (i & 3)) {           // peel to 16B alignment
        acc += g_nrm2[i] * g_xs2[g_src2[i] * FDIM + f];
        ++i;
    }
    for (; i + 8 <= end; i += 8) {
        iv4 sa = nt_i4(g_src2 + i);
        iv4 sb = nt_i4(g_src2 + i + 4);
        fv4 na = nt_f4(g_nrm2 + i);
        fv4 nb = nt_f4(g_nrm2 + i + 4);
        float xa0 = g_xs2[sa[0] * FDIM + f], xa1 = g_xs2[sa[1] * FDIM + f];
        float xa2 = g_xs2[sa[2] * FDIM + f], xa3 = g_xs2[sa[3] * FDIM + f];
        float xb0 = g_xs2[sb[0] * FDIM + f], xb1 = g_xs2[sb[1] * FDIM + f];
        float xb2 = g_xs2[sb[2] * FDIM + f], xb3 = g_xs2[sb[3] * FDIM + f];
        acc  += na[0] * xa0 + na[1] * xa1 + na[2] * xa2 + na[3] * xa3;
        accB += nb[0] * xb0 + nb[1] * xb1 + nb[2] * xb2 + nb[3] * xb3;
    }
    for (; i + 4 <= end; i += 4) {
        iv4 s4 = nt_i4(g_src2 + i);
        fv4 n4 = nt_f4(g_nrm2 + i);
        acc += n4[0] * g_xs2[s4[0] * FDIM + f] + n4[1] * g_xs2[s4[1] * FDIM + f]
             + n4[2] * g_xs2[s4[2] * FDIM + f] + n4[3] * g_xs2[s4[3] * FDIM + f];
    }
    for (; i < end; ++i) acc += g_nrm2[i] * g_xs2[g_src2[i] * FDIM + f];
    float dvn = g_deg[node];               // broadcast load (32 lanes same addr)
    g_tx1[node * FDIM + f] = dvn * (acc + accB);
}

// 64 nodes per 256-thread block. Thread (grp, j) accumulates output feature j
// of gates i,c,o for 8 nodes. k processed in chunks of 4: x/t read as float4
// broadcasts (b128, conflict-free), weights b32 coalesced.
__global__ __launch_bounds__(256, 4) void gates64_kernel(
    const float* __restrict__ x,
    const float* __restrict__ Wx, const float* __restrict__ bx,
    const float* __restrict__ bh, const float* __restrict__ wc,
    const float* __restrict__ bg, const float* __restrict__ lin_w,
    const float* __restrict__ lin_b, float* __restrict__ out, int n_nodes) {
    __shared__ float Ws[3 * 2048];      // gates {i,c,o} x K=2 x 32x32 = 24 KB
    __shared__ float xs[GNB * FDIM];    // 8 KB
    __shared__ float ts[GNB * FDIM];    // 8 KB

    for (int idx = threadIdx.x; idx < 512; idx += 256) {
        *(float4*)&Ws[idx * 4]        = *(const float4*)&Wx[0 * 2048 + idx * 4];
        *(float4*)&Ws[2048 + idx * 4] = *(const float4*)&Wx[2 * 2048 + idx * 4];
        *(float4*)&Ws[4096 + idx * 4] = *(const float4*)&Wx[3 * 2048 + idx * 4];
    }
    int node0 = blockIdx.x * GNB;
    for (int t = threadIdx.x; t < GNB * FDIM / 4; t += 256) {
        int q = t * 4;
        int n = node0 + (q >> 5);
        float4 xv = make_float4(0.f, 0.f, 0.f, 0.f);
        float4 tv = make_float4(0.f, 0.f, 0.f, 0.f);
        if (n < n_nodes) {
            xv = *(const float4*)&x[n * FDIM + (q & 31)];
            tv = *(const float4*)&g_tx1[n * FDIM + (q & 31)];
        }
        *(float4*)&xs[q] = xv;
        *(float4*)&ts[q] = tv;
    }
    __syncthreads();

    int j   = threadIdx.x & 31;
    int grp = threadIdx.x >> 5;         // 0..7, handles nodes grp*8 .. grp*8+7

    float ai0=0.f,ai1=0.f,ai2=0.f,ai3=0.f,ai4=0.f,ai5=0.f,ai6=0.f,ai7=0.f;
    float ac0=0.f,ac1=0.f,ac2=0.f,ac3=0.f,ac4=0.f,ac5=0.f,ac6=0.f,ac7=0.f;
    float ao0=0.f,ao1=0.f,ao2=0.f,ao3=0.f,ao4=0.f,ao5=0.f,ao6=0.f,ao7=0.f;
    const float* xr = &xs[(grp * 8) * FDIM];
    const float* tr = &ts[(grp * 8) * FDIM];
    for (int k4 = 0; k4 < 32; k4 += 4) {
        float4 xv0 = *(const float4*)(xr + 0 * FDIM + k4);
        float4 xv1 = *(const float4*)(xr + 1 * FDIM + k4);
        float4 xv2 = *(const float4*)(xr + 2 * FDIM + k4);
        float4 xv3 = *(const float4*)(xr + 3 * FDIM + k4);
        float4 xv4 = *(const float4*)(xr + 4 * FDIM + k4);
        float4 xv5 = *(const float4*)(xr + 5 * FDIM + k4);
        float4 xv6 = *(const float4*)(xr + 6 * FDIM + k4);
        float4 xv7 = *(const float4*)(xr + 7 * FDIM + k4);
        float4 tv0 = *(const float4*)(tr + 0 * FDIM + k4);
        float4 tv1 = *(const float4*)(tr + 1 * FDIM + k4);
        float4 tv2 = *(const float4*)(tr + 2 * FDIM + k4);
        float4 tv3 = *(const float4*)(tr + 3 * FDIM + k4);
        float4 tv4 = *(const float4*)(tr + 4 * FDIM + k4);
        float4 tv5 = *(const float4*)(tr + 5 * FDIM + k4);
        float4 tv6 = *(const float4*)(tr + 6 * FDIM + k4);
        float4 tv7 = *(const float4*)(tr + 7 * FDIM + k4);
#define KSTEP(kc, COMP)                                        \
        {   int o0 = (k4 + kc) * 32 + j;                       \
            float wi0 = Ws[o0],        wi1 = Ws[1024 + o0];    \
            float wg0 = Ws[2048 + o0], wg1 = Ws[3072 + o0];    \
            float wo0 = Ws[4096 + o0], wo1 = Ws[5120 + o0];    \
            ai0 += xv0.COMP * wi0 + tv0.COMP * wi1;            \
            ac0 += xv0.COMP * wg0 + tv0.COMP * wg1;            \
            ao0 += xv0.COMP * wo0 + tv0.COMP * wo1;            \
            ai1 += xv1.COMP * wi0 + tv1.COMP * wi1;            \
            ac1 += xv1.COMP * wg0 + tv1.COMP * wg1;            \
            ao1 += xv1.COMP * wo0 + tv1.COMP * wo1;            \
            ai2 += xv2.COMP * wi0 + tv2.COMP * wi1;            \
            ac2 += xv2.COMP * wg0 + tv2.COMP * wg1;            \
            ao2 += xv2.COMP * wo0 + tv2.COMP * wo1;            \
            ai3 += xv3.COMP * wi0 + tv3.COMP * wi1;            \
            ac3 += xv3.COMP * wg0 + tv3.COMP * wg1;            \
            ao3 += xv3.COMP * wo0 + tv3.COMP * wo1;            \
            ai4 += xv4.COMP * wi0 + tv4.COMP * wi1;            \
            ac4 += xv4.COMP * wg0 + tv4.COMP * wg1;            \
            ao4 += xv4.COMP * wo0 + tv4.COMP * wo1;            \
            ai5 += xv5.COMP * wi0 + tv5.COMP * wi1;            \
            ac5 += xv5.COMP * wg0 + tv5.COMP * wg1;            \
            ao5 += xv5.COMP * wo0 + tv5.COMP * wo1;            \
            ai6 += xv6.COMP * wi0 + tv6.COMP * wi1;            \
            ac6 += xv6.COMP * wg0 + tv6.COMP * wg1;            \
            ao6 += xv6.COMP * wo0 + tv6.COMP * wo1;            \
            ai7 += xv7.COMP * wi0 + tv7.COMP * wi1;            \
            ac7 += xv7.COMP * wg0 + tv7.COMP * wg1;            \
            ao7 += xv7.COMP * wo0 + tv7.COMP * wo1;            \
        }
        KSTEP(0, x) KSTEP(1, y) KSTEP(2, z) KSTEP(3, w)
#undef KSTEP
    }

    float bi = bx[0 * 32 + j] + bh[0 * 32 + j] + bg[0 * 32 + j];
    float bc = bx[2 * 32 + j] + bh[2 * 32 + j] + bg[2 * 32 + j];
    float bo = bx[3 * 32 + j] + bh[3 * 32 + j] + bg[3 * 32 + j];
    float wcp = wc[2 * 32 + j];
    float lwj = lin_w[j];
    float lb0 = lin_b[0];

#define GOUT(m, AI, AC, AO)                                            \
    {   int n = node0 + grp * 8 + m;                                   \
        float I = 1.f / (1.f + __expf(-(AI + bi)));                    \
        float T = tanhf(AC + bc);                                      \
        float C = I * T;                                               \
        float O = 1.f / (1.f + __expf(-(AO + bo + wcp * C)));          \
        float H = O * tanhf(C);                                        \
        float r = fmaxf(H, 0.f) * lwj;                                 \
        _Pragma("unroll")                                              \
        for (int mm = 16; mm > 0; mm >>= 1) r += __shfl_xor(r, mm, 32);\
        if (j == 0 && n < n_nodes) out[n] = r + lb0; }
    GOUT(0, ai0, ac0, ao0) GOUT(1, ai1, ac1, ao1)
    GOUT(2, ai2, ac2, ao2) GOUT(3, ai3, ac3, ao3)
    GOUT(4, ai4, ac4, ao4) GOUT(5, ai5, ac5, ao5)
    GOUT(6, ai6, ac6, ao6) GOUT(7, ai7, ac7, ao7)
#undef GOUT
}

extern "C" void kernel_launch(void* const* d_in, const int* in_sizes, int n_in,
                              void* d_out, int out_size, void* d_ws, size_t ws_size,
                              hipStream_t stream) {
    const float* x     = (const float*)d_in[0];
    const int*   ei    = (const int*)d_in[1];      // int32 on device
    const float* w     = (const float*)d_in[2];
    const float* Wx    = (const float*)d_in[3];
    const float* bx    = (const float*)d_in[4];
    // d_in[5] = Wh: unused (H=0)
    const float* bh    = (const float*)d_in[6];
    const float* wc    = (const float*)d_in[7];
    const float* bg    = (const float*)d_in[8];
    const float* lin_w = (const float*)d_in[9];
    const float* lin_b = (const float*)d_in[10];
    float*       out   = (float*)d_out;

    int n_nodes = in_sizes[0] / FDIM;
    if (n_nodes > MAX_N) n_nodes = MAX_N;
    int E = in_sizes[2];
    if (E > MAX_E) E = MAX_E;

    int nbuck   = (n_nodes + CB - 1) >> CBSH;            // 391 for N=100k
    int per_blk = (((E + NBLK - 1) / NBLK) + 3) & ~3;    // 3128, x4-aligned ranges
    int n_scan  = 2 * nbuck * NBLK + 1;                  // 400385
    int nb_scan = (n_scan + SCAN_TILE - 1) / SCAN_TILE;  // 196 (<= 256 for local scans)

    hist2_kernel<<<NBLK, 256, 0, stream>>>(ei, E, n_nodes, nbuck, per_blk);
    scan1_kernel<<<nb_scan, 256, 0, stream>>>(n_scan);
    scatter_burst_kernel<<<NBLK, 256, 0, stream>>>(ei, w, E, n_nodes, nbuck,
                                                   per_blk, nb_scan);
    sortdeg_kernel<<<nbuck, 1024, 0, stream>>>(x, E, n_nodes, nbuck, nb_scan);
    {
        long long tot = (long long)n_nodes * 32;
        gather_kernel<<<(int)((tot + 255) / 256), 256, 0, stream>>>(n_nodes);
    }
    gates64_kernel<<<(n_nodes + GNB - 1) / GNB, 256, 0, stream>>>(
        x, Wx, bx, bh, wc, bg, lin_w, lin_b, out, n_nodes);
}

// Round 18
// 248.397 us; speedup vs baseline: 1.0253x; 1.0253x over previous
//
#include <hip/hip_runtime.h>

// LSTM-GCN single step from (H=0, C=0).
// Collapsed math: Fg gate dead (C_prev=0), cheb(H,..)=bh, peephole wc[0],wc[1] dead.
//
// R22: R21 (254.7) regressed vs R19 (248.1): gather's FETCH went 86->160MB
// because g_xs2 is a freshly-written intermediate -- unlike the read-only x
// (L3-resident across dispatches), its random re-reads went to HBM. Lesson:
// never reroute a random-access stream through a freshly-written copy.
// R22 = R19's proven pipeline (x-reading gather, dinv folded into nrm by
// fine_sort, separate deg_sum) at 7 dispatches: keep R21's scan2 deletion
// (consumers scan the 196 raw tile sums locally -- verified sound).

#define FDIM 32
#define MAX_N 100000
#define MAX_E 1600000
#define CBSH 8                                // 256 nodes per coarse bucket
#define CB 256
#define MAX_NB ((MAX_N + CB - 1) / CB)        // 391 buckets max
#define NBLK 512                              // blocks in each edge pass
#define SCAN_TILE 2048                        // elements per scan block (256 thr x 8)
#define GNB 64                                // nodes per gates block
#define PERBLK 3136                           // staged records per block (>= 3128)

typedef int   iv4 __attribute__((ext_vector_type(4)));
typedef float fv4 __attribute__((ext_vector_type(4)));
__device__ __forceinline__ iv4 nt_i4(const int* p)   { return __builtin_nontemporal_load((const iv4*)p); }
__device__ __forceinline__ fv4 nt_f4(const float* p) { return __builtin_nontemporal_load((const fv4*)p); }

__device__ float g_deg[MAX_N];                    // dinv (written by deg_sum)
__device__ int   g_part2[2 * MAX_NB * NBLK + 1];  // [dst bins | src bins] counts->offsets
__device__ int   g_blk[1024];                     // RAW scan tile sums (no scan2)
__device__ uint2 g_rec[MAX_E];                    // dst-sorted {src<<8|dst_loc, w}
__device__ uint2 g_srec[MAX_E];                   // src-sorted {src_loc, w}
__device__ int   g_row[MAX_N + 1];                // per-node CSR row starts
__device__ __attribute__((aligned(16))) int   g_src2[MAX_E];   // CSR src, node-sorted
__device__ __attribute__((aligned(16))) float g_nrm2[MAX_E];   // CSR nrm, node-sorted
__device__ float g_tx1[MAX_N * FDIM];             // L_hat @ x

// One edge pass, NO global atomics: dual LDS histograms of dst>>8 and src>>8,
// flushed non-atomically to g_part2[bin*NBLK + block]. Edge reads int4.
__global__ __launch_bounds__(256) void hist2_kernel(const int* __restrict__ ei,
                                                    int E, int n_nodes, int nbuck,
                                                    int per_blk) {
    __shared__ int hd[MAX_NB];
    __shared__ int hs[MAX_NB];
    for (int i = threadIdx.x; i < nbuck; i += 256) { hd[i] = 0; hs[i] = 0; }
    __syncthreads();
    int start = blockIdx.x * per_blk;            // per_blk % 4 == 0 -> aligned
    int end = start + per_blk;
    if (end > E) end = E;
    for (int base = start; base < end; base += 1024) {
        int e = base + threadIdx.x * 4;
        if (e + 4 <= end) {
            int4 s4 = *(const int4*)(ei + e);
            int4 d4 = *(const int4*)(ei + E + e);
#define H2(S, D) if ((unsigned)(S) < (unsigned)n_nodes && (unsigned)(D) < (unsigned)n_nodes) { \
                atomicAdd(&hd[(D) >> CBSH], 1); atomicAdd(&hs[(S) >> CBSH], 1); }
            H2(s4.x, d4.x) H2(s4.y, d4.y) H2(s4.z, d4.z) H2(s4.w, d4.w)
#undef H2
        } else if (e < end) {
            for (int q = e; q < end; ++q) {
                int s = ei[q], d = ei[E + q];
                if ((unsigned)s >= (unsigned)n_nodes || (unsigned)d >= (unsigned)n_nodes)
                    continue;
                atomicAdd(&hd[d >> CBSH], 1);
                atomicAdd(&hs[s >> CBSH], 1);
            }
        }
    }
    __syncthreads();
    for (int i = threadIdx.x; i < nbuck; i += 256) {
        g_part2[i * NBLK + blockIdx.x] = hd[i];
        g_part2[(nbuck + i) * NBLK + blockIdx.x] = hs[i];
    }
    if (blockIdx.x == 0 && threadIdx.x == 0)
        g_part2[2 * nbuck * NBLK] = 0;        // scan sentinel
}

// Per-tile exclusive scan; writes RAW tile totals to g_blk (consumers scan it
// locally -- scan2 kernel deleted). n ~ 400K -> 196 tiles (<= 256).
__global__ __launch_bounds__(256) void scan1_kernel(int n) {
    __shared__ int sh[256];
    int tid = threadIdx.x;
    int base = blockIdx.x * SCAN_TILE + tid * 8;
    int v[8];
#pragma unroll
    for (int i = 0; i < 8; ++i) v[i] = (base + i < n) ? g_part2[base + i] : 0;
    int tsum = 0;
#pragma unroll
    for (int i = 0; i < 8; ++i) tsum += v[i];
    sh[tid] = tsum;
    __syncthreads();
    for (int off = 1; off < 256; off <<= 1) {
        int t = (tid >= off) ? sh[tid - off] : 0;
        __syncthreads();
        sh[tid] += t;
        __syncthreads();
    }
    if (tid == 255) g_blk[blockIdx.x] = sh[255];
    int run = sh[tid] - tsum;   // exclusive offset within tile
#pragma unroll
    for (int i = 0; i < 8; ++i) {
        if (base + i < n) g_part2[base + i] = run;
        run += v[i];
    }
}

// Two phases (dst records into g_rec, src records into g_srec). Tile offsets
// scanned locally from raw g_blk. Per phase: counts/bases from the scanned
// matrix, 512-wide LDS Hillis-Steele for local run bases, cursor-scatter into
// staged LDS + per-record global position, then coalesced burst write-out.
__global__ __launch_bounds__(256) void scatter_burst_kernel(const int* __restrict__ ei,
                                                            const float* __restrict__ w,
                                                            int E, int n_nodes, int nbuck,
                                                            int per_blk, int ntile) {
    __shared__ int   toff[256];
    __shared__ int   cnt[512];
    __shared__ int   sc[512];
    __shared__ int   gb[MAX_NB];
    __shared__ int   cur[MAX_NB];
    __shared__ uint2 staged[PERBLK];
    __shared__ int   gpos[PERBLK];
    int tid = threadIdx.x;
    int blk = blockIdx.x;
    int start = blk * per_blk;
    int end = start + per_blk;
    if (end > E) end = E;

    // local exclusive scan of raw tile sums (ntile <= 256)
    int orig = (tid < ntile) ? g_blk[tid] : 0;
    toff[tid] = orig;
    __syncthreads();
    for (int off = 1; off < 256; off <<= 1) {
        int v = (tid >= off) ? toff[tid - off] : 0;
        __syncthreads();
        toff[tid] += v;
        __syncthreads();
    }
    toff[tid] -= orig;                         // exclusive
    __syncthreads();
#define SCN(idx) (g_part2[idx] + toff[(idx) >> 11])

    for (int phase = 0; phase < 2; ++phase) {
        cnt[tid] = 0; cnt[tid + 256] = 0;
        __syncthreads();
        for (int i = tid; i < nbuck; i += 256) {
            int flat = (phase * nbuck + i) * NBLK + blk;
            int g0 = SCN(flat);
            int g1 = SCN(flat + 1);                // flat successor = run end
            gb[i] = g0 - phase * E;                // src space is [E,2E)
            cnt[i] = g1 - g0;
        }
        __syncthreads();
        sc[tid] = cnt[tid]; sc[tid + 256] = cnt[tid + 256];
        __syncthreads();
        for (int off = 1; off < 512; off <<= 1) {  // inclusive scan, 512 wide
            int v0 = (tid >= off) ? sc[tid - off] : 0;
            int v1 = sc[tid + 256 - off];          // tid+256 >= off always
            __syncthreads();
            sc[tid] += v0; sc[tid + 256] += v1;
            __syncthreads();
        }
        for (int i = tid; i < nbuck; i += 256) cur[i] = sc[i] - cnt[i];
        __syncthreads();
#define SB1(S, D, W)                                                            \
        {   int s = (S), d = (D);                                               \
            if ((unsigned)s < (unsigned)n_nodes && (unsigned)d < (unsigned)n_nodes) { \
                int key = phase ? s : d;                                        \
                int bin = key >> CBSH;                                          \
                float w0 = (s == d) ? 0.f : (W);   /* self-loops: w=0 */        \
                unsigned pay = phase ? (unsigned)(s & (CB - 1))                 \
                    : (((unsigned)s << CBSH) | (unsigned)(d & (CB - 1)));       \
                int p = atomicAdd(&cur[bin], 1);   /* LDS cursor */             \
                staged[p] = make_uint2(pay, __float_as_uint(w0));               \
                gpos[p] = gb[bin] + (p - (sc[bin] - cnt[bin]));                 \
            } }
        for (int base = start; base < end; base += 1024) {
            int e = base + tid * 4;
            if (e + 4 <= end) {
                iv4 s4 = nt_i4(ei + e);
                iv4 d4 = nt_i4(ei + E + e);
                fv4 w4 = nt_f4(w + e);
                SB1(s4[0], d4[0], w4[0]) SB1(s4[1], d4[1], w4[1])
                SB1(s4[2], d4[2], w4[2]) SB1(s4[3], d4[3], w4[3])
            } else if (e < end) {
                for (int q = e; q < end; ++q) SB1(ei[q], ei[E + q], w[q])
            }
        }
#undef SB1
        __syncthreads();
        int tot = sc[511];                         // valid records in this chunk
        if (phase == 0) {
            for (int t = tid; t < tot; t += 256) g_rec[gpos[t]] = staged[t];
        } else {
            for (int t = tid; t < tot; t += 256) g_srec[gpos[t]] = staged[t];
        }
        __syncthreads();
    }
#undef SCN
}

// One block per src bucket (256 nodes), 1024 threads. Local tile-sum scan, then
// LDS f32 accumulate w per local node, then write dinv = rsqrt(deg).
__global__ __launch_bounds__(1024) void deg_sum_kernel(int E, int n_nodes, int nbuck,
                                                       int ntile) {
    __shared__ int   toff[256];
    __shared__ float ldeg[CB];
    int tid = threadIdx.x;
    int b = blockIdx.x;
    int orig = 0;
    if (tid < 256) { orig = (tid < ntile) ? g_blk[tid] : 0; toff[tid] = orig; }
    __syncthreads();
    for (int off = 1; off < 256; off <<= 1) {
        int v = (tid < 256 && tid >= off) ? toff[tid - off] : 0;
        __syncthreads();
        if (tid < 256) toff[tid] += v;
        __syncthreads();
    }
    if (tid < 256) toff[tid] -= orig;          // exclusive
    if (tid < CB) ldeg[tid] = 0.f;
    __syncthreads();
#define SCN(idx) (g_part2[idx] + toff[(idx) >> 11])
    int rs = SCN((nbuck + b) * NBLK) - E;
    int re = SCN((nbuck + b + 1) * NBLK) - E;  // b==nbuck-1 hits sentinel (2E)
#undef SCN
    for (int i = rs + tid; i < re; i += 1024) {
        uint2 r = g_srec[i];
        atomicAdd(&ldeg[r.x], __uint_as_float(r.y));   // LDS atomic
    }
    __syncthreads();
    if (tid < CB) {
        int node = (b << CBSH) + tid;
        if (node < n_nodes) {
            float dg = ldeg[tid];
            g_deg[node] = (dg > 0.f) ? rsqrtf(dg) : 0.f;
        }
    }
}

// One block per dst bucket (256 nodes, ~4096 records), 1024 threads. Local
// tile-sum scan, count local nodes, hierarchical scan (uniform barriers) ->
// absolute g_row, then reorder into per-node CSR with nrm = -dinv[s]*w*dinv[d]
// (dinv is 400 KB -> L2-resident; bucket-side dinv staged in LDS).
__global__ __launch_bounds__(1024) void fine_sort_kernel(int E, int n_nodes, int nbuck,
                                                         int ntile) {
    __shared__ int   toff[256];
    __shared__ int   cnt[CB];
    __shared__ int   cur[CB];
    __shared__ float dv[CB];
    __shared__ int   wsum[4];
    int tid = threadIdx.x;
    int b = blockIdx.x;
    int orig = 0;
    if (tid < 256) { orig = (tid < ntile) ? g_blk[tid] : 0; toff[tid] = orig; }
    __syncthreads();
    for (int off = 1; off < 256; off <<= 1) {
        int v = (tid < 256 && tid >= off) ? toff[tid - off] : 0;
        __syncthreads();
        if (tid < 256) toff[tid] += v;
        __syncthreads();
    }
    if (tid < 256) toff[tid] -= orig;          // exclusive
    if (tid < CB) {
        cnt[tid] = 0;
        int node = (b << CBSH) + tid;
        dv[tid] = (node < n_nodes) ? g_deg[node] : 0.f;
    }
    __syncthreads();
#define SCN(idx) (g_part2[idx] + toff[(idx) >> 11])
    int rs = SCN(b * NBLK);
    int re = SCN((b + 1) * NBLK);              // b==nbuck-1 hits first src bin (= E)
#undef SCN
    for (int i = rs + tid; i < re; i += 1024)
        atomicAdd(&cnt[g_rec[i].x & (CB - 1)], 1);
    __syncthreads();
    {   // hierarchical scan, UNIFORM barriers (all 16 waves run; >=4 discarded)
        int lane = tid & 63;
        int wave = tid >> 6;
        int v = (tid < CB) ? cnt[tid] : 0;
        int inc = v;
#pragma unroll
        for (int off = 1; off < 64; off <<= 1) {
            int t = __shfl_up(inc, off, 64);
            if (lane >= off) inc += t;
        }
        if (tid < CB && lane == 63) wsum[wave] = inc;
        __syncthreads();                       // uniform
        if (tid < CB) {
            int wo = 0;
#pragma unroll
            for (int ww = 0; ww < 4; ++ww) wo += (ww < wave) ? wsum[ww] : 0;
            int start = rs + wo + (inc - v);   // exclusive
            cur[tid] = start;
            int node = (b << CBSH) + tid;
            if (node < n_nodes) g_row[node] = start;
        }
    }
    if (b == nbuck - 1 && tid == 0) g_row[n_nodes] = re;
    __syncthreads();
    for (int i = rs + tid; i < re; i += 1024) {
        uint2 r = g_rec[i];
        int s = (int)(r.x >> CBSH);
        int loc = r.x & (CB - 1);
        float nrm = -g_deg[s] * __uint_as_float(r.y) * dv[loc];
        int pos = atomicAdd(&cur[loc], 1);     // LDS atomic
        g_src2[pos] = s;
        g_nrm2[pos] = nrm;
    }
}

// Half-wave (32 lanes = 32 features) per node, REGISTER accumulators (dual),
// CSR stream nt, 8-deep unroll. Reads the READ-ONLY x (L3-resident across
// dispatches -- R21 proved rerouting through a written copy doubles HBM fetch).
__global__ __launch_bounds__(256) void gather_kernel(const float* __restrict__ x,
                                                     int n_nodes) {
    int t = blockIdx.x * blockDim.x + threadIdx.x;
    int node = t >> 5;
    int f = t & 31;
    if (node >= n_nodes) return;
    int i = g_row[node];
    int end = g_row[node + 1];
    float acc = 0.f, accB = 0.f;
    while (i < end && (i & 3)) {           // peel to 16B alignment
        acc += g_nrm2[i] * x[g_src2[i] * FDIM + f];
        ++i;
    }
    for (; i + 8 <= end; i += 8) {
        iv4 sa = nt_i4(g_src2 + i);
        iv4 sb = nt_i4(g_src2 + i + 4);
        fv4 na = nt_f4(g_nrm2 + i);
        fv4 nb = nt_f4(g_nrm2 + i + 4);
        float xa0 = x[sa[0] * FDIM + f], xa1 = x[sa[1] * FDIM + f];
        float xa2 = x[sa[2] * FDIM + f], xa3 = x[sa[3] * FDIM + f];
        float xb0 = x[sb[0] * FDIM + f], xb1 = x[sb[1] * FDIM + f];
        float xb2 = x[sb[2] * FDIM + f], xb3 = x[sb[3] * FDIM + f];
        acc  += na[0] * xa0 + na[1] * xa1 + na[2] * xa2 + na[3] * xa3;
        accB += nb[0] * xb0 + nb[1] * xb1 + nb[2] * xb2 + nb[3] * xb3;
    }
    for (; i + 4 <= end; i += 4) {
        iv4 s4 = nt_i4(g_src2 + i);
        fv4 n4 = nt_f4(g_nrm2 + i);
        acc += n4[0] * x[s4[0] * FDIM + f] + n4[1] * x[s4[1] * FDIM + f]
             + n4[2] * x[s4[2] * FDIM + f] + n4[3] * x[s4[3] * FDIM + f];
    }
    for (; i < end; ++i) acc += g_nrm2[i] * x[g_src2[i] * FDIM + f];
    g_tx1[node * FDIM + f] = acc + accB;
}

// 64 nodes per 256-thread block. Thread (grp, j) accumulates output feature j
// of gates i,c,o for 8 nodes. k processed in chunks of 4: x/t read as float4
// broadcasts (b128, conflict-free), weights b32 coalesced.
__global__ __launch_bounds__(256, 4) void gates64_kernel(
    const float* __restrict__ x,
    const float* __restrict__ Wx, const float* __restrict__ bx,
    const float* __restrict__ bh, const float* __restrict__ wc,
    const float* __restrict__ bg, const float* __restrict__ lin_w,
    const float* __restrict__ lin_b, float* __restrict__ out, int n_nodes) {
    __shared__ float Ws[3 * 2048];      // gates {i,c,o} x K=2 x 32x32 = 24 KB
    __shared__ float xs[GNB * FDIM];    // 8 KB
    __shared__ float ts[GNB * FDIM];    // 8 KB

    for (int idx = threadIdx.x; idx < 512; idx += 256) {
        *(float4*)&Ws[idx * 4]        = *(const float4*)&Wx[0 * 2048 + idx * 4];
        *(float4*)&Ws[2048 + idx * 4] = *(const float4*)&Wx[2 * 2048 + idx * 4];
        *(float4*)&Ws[4096 + idx * 4] = *(const float4*)&Wx[3 * 2048 + idx * 4];
    }
    int node0 = blockIdx.x * GNB;
    for (int t = threadIdx.x; t < GNB * FDIM / 4; t += 256) {
        int q = t * 4;
        int n = node0 + (q >> 5);
        float4 xv = make_float4(0.f, 0.f, 0.f, 0.f);
        float4 tv = make_float4(0.f, 0.f, 0.f, 0.f);
        if (n < n_nodes) {
            xv = *(const float4*)&x[n * FDIM + (q & 31)];
            tv = *(const float4*)&g_tx1[n * FDIM + (q & 31)];
        }
        *(float4*)&xs[q] = xv;
        *(float4*)&ts[q] = tv;
    }
    __syncthreads();

    int j   = threadIdx.x & 31;
    int grp = threadIdx.x >> 5;         // 0..7, handles nodes grp*8 .. grp*8+7

    float ai0=0.f,ai1=0.f,ai2=0.f,ai3=0.f,ai4=0.f,ai5=0.f,ai6=0.f,ai7=0.f;
    float ac0=0.f,ac1=0.f,ac2=0.f,ac3=0.f,ac4=0.f,ac5=0.f,ac6=0.f,ac7=0.f;
    float ao0=0.f,ao1=0.f,ao2=0.f,ao3=0.f,ao4=0.f,ao5=0.f,ao6=0.f,ao7=0.f;
    const float* xr = &xs[(grp * 8) * FDIM];
    const float* tr = &ts[(grp * 8) * FDIM];
    for (int k4 = 0; k4 < 32; k4 += 4) {
        float4 xv0 = *(const float4*)(xr + 0 * FDIM + k4);
        float4 xv1 = *(const float4*)(xr + 1 * FDIM + k4);
        float4 xv2 = *(const float4*)(xr + 2 * FDIM + k4);
        float4 xv3 = *(const float4*)(xr + 3 * FDIM + k4);
        float4 xv4 = *(const float4*)(xr + 4 * FDIM + k4);
        float4 xv5 = *(const float4*)(xr + 5 * FDIM + k4);
        float4 xv6 = *(const float4*)(xr + 6 * FDIM + k4);
        float4 xv7 = *(const float4*)(xr + 7 * FDIM + k4);
        float4 tv0 = *(const float4*)(tr + 0 * FDIM + k4);
        float4 tv1 = *(const float4*)(tr + 1 * FDIM + k4);
        float4 tv2 = *(const float4*)(tr + 2 * FDIM + k4);
        float4 tv3 = *(const float4*)(tr + 3 * FDIM + k4);
        float4 tv4 = *(const float4*)(tr + 4 * FDIM + k4);
        float4 tv5 = *(const float4*)(tr + 5 * FDIM + k4);
        float4 tv6 = *(const float4*)(tr + 6 * FDIM + k4);
        float4 tv7 = *(const float4*)(tr + 7 * FDIM + k4);
#define KSTEP(kc, COMP)                                        \
        {   int o0 = (k4 + kc) * 32 + j;                       \
            float wi0 = Ws[o0],        wi1 = Ws[1024 + o0];    \
            float wg0 = Ws[2048 + o0], wg1 = Ws[3072 + o0];    \
            float wo0 = Ws[4096 + o0], wo1 = Ws[5120 + o0];    \
            ai0 += xv0.COMP * wi0 + tv0.COMP * wi1;            \
            ac0 += xv0.COMP * wg0 + tv0.COMP * wg1;            \
            ao0 += xv0.COMP * wo0 + tv0.COMP * wo1;            \
            ai1 += xv1.COMP * wi0 + tv1.COMP * wi1;            \
            ac1 += xv1.COMP * wg0 + tv1.COMP * wg1;            \
            ao1 += xv1.COMP * wo0 + tv1.COMP * wo1;            \
            ai2 += xv2.COMP * wi0 + tv2.COMP * wi1;            \
            ac2 += xv2.COMP * wg0 + tv2.COMP * wg1;            \
            ao2 += xv2.COMP * wo0 + tv2.COMP * wo1;            \
            ai3 += xv3.COMP * wi0 + tv3.COMP * wi1;            \
            ac3 += xv3.COMP * wg0 + tv3.COMP * wg1;            \
            ao3 += xv3.COMP * wo0 + tv3.COMP * wo1;            \
            ai4 += xv4.COMP * wi0 + tv4.COMP * wi1;            \
            ac4 += xv4.COMP * wg0 + tv4.COMP * wg1;            \
            ao4 += xv4.COMP * wo0 + tv4.COMP * wo1;            \
            ai5 += xv5.COMP * wi0 + tv5.COMP * wi1;            \
            ac5 += xv5.COMP * wg0 + tv5.COMP * wg1;            \
            ao5 += xv5.COMP * wo0 + tv5.COMP * wo1;            \
            ai6 += xv6.COMP * wi0 + tv6.COMP * wi1;            \
            ac6 += xv6.COMP * wg0 + tv6.COMP * wg1;            \
            ao6 += xv6.COMP * wo0 + tv6.COMP * wo1;            \
            ai7 += xv7.COMP * wi0 + tv7.COMP * wi1;            \
            ac7 += xv7.COMP * wg0 + tv7.COMP * wg1;            \
            ao7 += xv7.COMP * wo0 + tv7.COMP * wo1;            \
        }
        KSTEP(0, x) KSTEP(1, y) KSTEP(2, z) KSTEP(3, w)
#undef KSTEP
    }

    float bi = bx[0 * 32 + j] + bh[0 * 32 + j] + bg[0 * 32 + j];
    float bc = bx[2 * 32 + j] + bh[2 * 32 + j] + bg[2 * 32 + j];
    float bo = bx[3 * 32 + j] + bh[3 * 32 + j] + bg[3 * 32 + j];
    float wcp = wc[2 * 32 + j];
    float lwj = lin_w[j];
    float lb0 = lin_b[0];

#define GOUT(m, AI, AC, AO)                                            \
    {   int n = node0 + grp * 8 + m;                                   \
        float I = 1.f / (1.f + __expf(-(AI + bi)));                    \
        float T = tanhf(AC + bc);                                      \
        float C = I * T;                                               \
        float O = 1.f / (1.f + __expf(-(AO + bo + wcp * C)));          \
        float H = O * tanhf(C);                                        \
        float r = fmaxf(H, 0.f) * lwj;                                 \
        _Pragma("unroll")                                              \
        for (int mm = 16; mm > 0; mm >>= 1) r += __shfl_xor(r, mm, 32);\
        if (j == 0 && n < n_nodes) out[n] = r + lb0; }
    GOUT(0, ai0, ac0, ao0) GOUT(1, ai1, ac1, ao1)
    GOUT(2, ai2, ac2, ao2) GOUT(3, ai3, ac3, ao3)
    GOUT(4, ai4, ac4, ao4) GOUT(5, ai5, ac5, ao5)
    GOUT(6, ai6, ac6, ao6) GOUT(7, ai7, ac7, ao7)
#undef GOUT
}

extern "C" void kernel_launch(void* const* d_in, const int* in_sizes, int n_in,
                              void* d_out, int out_size, void* d_ws, size_t ws_size,
                              hipStream_t stream) {
    const float* x     = (const float*)d_in[0];
    const int*   ei    = (const int*)d_in[1];      // int32 on device
    const float* w     = (const float*)d_in[2];
    const float* Wx    = (const float*)d_in[3];
    const float* bx    = (const float*)d_in[4];
    // d_in[5] = Wh: unused (H=0)
    const float* bh    = (const float*)d_in[6];
    const float* wc    = (const float*)d_in[7];
    const float* bg    = (const float*)d_in[8];
    const float* lin_w = (const float*)d_in[9];
    const float* lin_b = (const float*)d_in[10];
    float*       out   = (float*)d_out;

    int n_nodes = in_sizes[0] / FDIM;
    if (n_nodes > MAX_N) n_nodes = MAX_N;
    int E = in_sizes[2];
    if (E > MAX_E) E = MAX_E;

    int nbuck   = (n_nodes + CB - 1) >> CBSH;            // 391 for N=100k
    int per_blk = (((E + NBLK - 1) / NBLK) + 3) & ~3;    // 3128, x4-aligned ranges
    int n_scan  = 2 * nbuck * NBLK + 1;                  // 400385
    int nb_scan = (n_scan + SCAN_TILE - 1) / SCAN_TILE;  // 196 (<= 256 for local scans)

    hist2_kernel<<<NBLK, 256, 0, stream>>>(ei, E, n_nodes, nbuck, per_blk);
    scan1_kernel<<<nb_scan, 256, 0, stream>>>(n_scan);
    scatter_burst_kernel<<<NBLK, 256, 0, stream>>>(ei, w, E, n_nodes, nbuck,
                                                   per_blk, nb_scan);
    deg_sum_kernel<<<nbuck, 1024, 0, stream>>>(E, n_nodes, nbuck, nb_scan);
    fine_sort_kernel<<<nbuck, 1024, 0, stream>>>(E, n_nodes, nbuck, nb_scan);
    {
        long long tot = (long long)n_nodes * 32;
        gather_kernel<<<(int)((tot + 255) / 256), 256, 0, stream>>>(x, n_nodes);
    }
    gates64_kernel<<<(n_nodes + GNB - 1) / GNB, 256, 0, stream>>>(
        x, Wx, bx, bh, wc, bg, lin_w, lin_b, out, n_nodes);
}